// Round 18
// baseline (163.067 us; speedup 1.0000x reference)
//
#include <hip/hip_runtime.h>
#include <math.h>

// Damping: B=32768, N=64, H=256, OFF=2016
//   diag: x -> tanh(Wd1) -> tanh(Wd2) -> Wdo   (64 per sample)
//   off : x -> tanh(Wo1) -> tanh(Wo2) -> Woo   (2016 per sample, strict lower tri)
//   out = L (L^T x0), L diag = xd, L[i][j](j<i) = z[i(i-1)/2+j]
//
// z path: gemm_z (128x128 tile, double-buffered 2-phase overlap, 2 WG/CU)
// -> HBM pair-interleaved padded-triangle groups -> apply (wave-local).

#define B_TOT 32768
#define NDIM  64
#define HDIM  256
#define OFFD  2016
#define GRP_UNITS 67584            // 16 pairs * 4224 bf16 units per 32-sample group
#define GRP_BYTES 135168

typedef __bf16 bf16x8 __attribute__((ext_vector_type(8)));
typedef float  f32x4  __attribute__((ext_vector_type(4)));

__device__ __forceinline__ float fast_tanh(float x) {
  float e = __expf(2.f * x);
  return 1.f - 2.f * __builtin_amdgcn_rcpf(e + 1.f);
}
__device__ __forceinline__ float lane_bcast(float v, int l) {
  return __uint_as_float(__builtin_amdgcn_readlane(__float_as_uint(v), l));
}
__device__ __forceinline__ float bf_lo(unsigned w) { return __uint_as_float(w << 16); }
__device__ __forceinline__ float bf_hi(unsigned w) { return __uint_as_float(w & 0xffff0000u); }
__device__ __forceinline__ unsigned bfbits(float f) {
  __bf16 h = (__bf16)f;
  return (unsigned)__builtin_bit_cast(unsigned short, h);
}
// padded-triangle row start (units of offv): row i occupies [rs(i), rs(i)+ceil4(i))
__device__ __forceinline__ int rs_of(int i) {
  const int a3 = i & 3;
  return ((i * (i - 1)) >> 1) + 6 * (i >> 2) + ((a3 == 2) ? 3 : (a3 == 3) ? 5 : 0);
}

__device__ __forceinline__ void gload_lds16(const void* g, void* l) {
  __builtin_amdgcn_global_load_lds(
      (const __attribute__((address_space(1))) unsigned*)g,
      (__attribute__((address_space(3))) unsigned*)l, 16, 0, 0);
}

#define MFMA(A, B, C) __builtin_amdgcn_mfma_f32_16x16x32_bf16((A), (B), (C), 0, 0, 0)
#define SB0() __builtin_amdgcn_sched_barrier(0)
// XOR-swizzled 16B-granule byte offset within a row (low 3 bits of granule)
#define GOFF(g, row) (((((g) & ~7) | (((g) & 7) ^ ((row) & 7)))) << 4)

// ---------------- weight cast (f32 -> bf16) + Woob pad zero-fill ----------------
__device__ __forceinline__ void cast_range(const float* __restrict__ s,
                                           __bf16* __restrict__ d, int n) {
  int i = blockIdx.x * blockDim.x + threadIdx.x;
  const int stride = gridDim.x * blockDim.x;
  for (; i < n; i += stride) d[i] = (__bf16)s[i];
}
__global__ __launch_bounds__(256) void cast_all_kernel(
    const float* s0, __bf16* d0, int n0, const float* s1, __bf16* d1, int n1,
    const float* s2, __bf16* d2, int n2, const float* s3, __bf16* d3, int n3,
    const float* s4, __bf16* d4, int n4, const float* s5, __bf16* d5, int n5,
    __bf16* d6, int n6) {
  cast_range(s0, d0, n0); cast_range(s1, d1, n1); cast_range(s2, d2, n2);
  cast_range(s3, d3, n3); cast_range(s4, d4, n4); cast_range(s5, d5, n5);
  int i = blockIdx.x * blockDim.x + threadIdx.x;
  const int stride = gridDim.x * blockDim.x;
  for (; i < n6; i += stride) d6[i] = (__bf16)0.f;
}

__device__ __forceinline__ bf16x8 cvt8(const float* __restrict__ p) {
  const float4 u = *(const float4*)p;
  const float4 v = *(const float4*)(p + 4);
  bf16x8 r;
  r[0] = (__bf16)u.x; r[1] = (__bf16)u.y; r[2] = (__bf16)u.z; r[3] = (__bf16)u.w;
  r[4] = (__bf16)v.x; r[5] = (__bf16)v.y; r[6] = (__bf16)v.z; r[7] = (__bf16)v.w;
  return r;
}

// ---------------- shared trunk machinery: 64 samples/WG, 72KB LDS, 2 WG/CU ------
#define TRK_SMEM (8192 + 32768 + 32768)

// stage one 16KB weight chunk; rows are 128B if c<2 else 512B
__device__ __forceinline__ void stage_chunk2(const char* wreg, char* wb,
                                             int c, int wave) {
  const char* base = wreg + (size_t)c * 16384;
  char* dst = wb + (c & 1) * 16384;
  const int lane = threadIdx.x & 63;
  const int s0 = wave * 64 + lane;
  const int s1 = s0 + 512;
  if (c < 2) {  // 128-byte rows (8 granules)
    const int r0 = s0 >> 3, q0 = (s0 & 7) ^ (r0 & 7);
    gload_lds16(base + r0 * 128 + (q0 << 4), dst + wave * 1024);
    const int r1 = s1 >> 3, q1 = (s1 & 7) ^ (r1 & 7);
    gload_lds16(base + r1 * 128 + (q1 << 4), dst + (wave + 8) * 1024);
  } else {      // 512-byte rows (32 granules)
    const int r0 = s0 >> 5, g0 = s0 & 31;
    const int q0 = (g0 & 24) | ((g0 & 7) ^ (r0 & 7));
    gload_lds16(base + r0 * 512 + (q0 << 4), dst + wave * 1024);
    const int r1 = s1 >> 5, g1 = s1 & 31;
    const int q1 = (g1 & 24) | ((g1 & 7) ^ (r1 & 7));
    gload_lds16(base + r1 * 512 + (q1 << 4), dst + (wave + 8) * 1024);
  }
}

// ---------------- off_trunk: x -> tanh(Wo1) -> tanh(Wo2) -> g2 ------------------
__global__ __launch_bounds__(512, 2) void off_trunk_kernel(
    const float* __restrict__ x, const __bf16* __restrict__ Wreg,
    const float* __restrict__ bo1, const float* __restrict__ bo2,
    __bf16* __restrict__ g2) {
  extern __shared__ char smem[];
  char* xa  = smem;            // 8 KB
  char* act = smem + 8192;     // 32 KB (g1)
  char* wb  = smem + 40960;    // 32 KB
  const char* Wc = (const char*)Wreg;

  const int tid = threadIdx.x;
  const int wave = tid >> 6, lane = tid & 63;
  const int lr = lane & 15, lg = lane >> 4;
  const int sb = blockIdx.x * 64;

  float bv1[2], bv2[8];
#pragma unroll
  for (int cc = 0; cc < 2; ++cc) bv1[cc] = bo1[cc * 128 + wave * 16 + lr];
#pragma unroll
  for (int cc = 0; cc < 8; ++cc) bv2[cc] = bo2[cc * 32 + (wave & 1) * 16 + lr];

  {
    const int s = tid >> 3, g = tid & 7;
    const bf16x8 v = cvt8(x + (size_t)(sb + s) * 64 + g * 8);
    *(bf16x8*)(xa + s * 128 + GOFF(g, s)) = v;
  }
  stage_chunk2(Wc, wb, 0, wave);
  __syncthreads();

#pragma unroll
  for (int cc = 0; cc < 2; ++cc) {
    stage_chunk2(Wc, wb, cc + 1, wave);
    const char* wbp = wb + (cc & 1) * 16384;
    const int brow = wave * 16 + lr;
    const bf16x8 b0 = *(const bf16x8*)(wbp + brow * 128 + GOFF(lg, brow));
    const bf16x8 b1 = *(const bf16x8*)(wbp + brow * 128 + GOFF(4 + lg, brow));
    const int ch = cc * 128 + brow;
#pragma unroll
    for (int m = 0; m < 4; ++m) {
      const int arow = m * 16 + lr;
      const bf16x8 a0 = *(const bf16x8*)(xa + arow * 128 + GOFF(lg, arow));
      const bf16x8 a1 = *(const bf16x8*)(xa + arow * 128 + GOFF(4 + lg, arow));
      f32x4 acc = {0.f, 0.f, 0.f, 0.f};
      acc = MFMA(a0, b0, acc);
      acc = MFMA(a1, b1, acc);
#pragma unroll
      for (int r = 0; r < 4; ++r) {
        const int s = m * 16 + lg * 4 + r;
        *(__bf16*)(act + s * 512 + GOFF(ch >> 3, s) + (ch & 7) * 2) =
            (__bf16)fast_tanh(acc[r] + bv1[cc]);
      }
    }
    __syncthreads();
  }

#pragma unroll
  for (int cc = 0; cc < 8; ++cc) {
    const int c = cc + 2;
    if (c + 1 < 10) stage_chunk2(Wc, wb, c + 1, wave);
    const char* wbp = wb + (c & 1) * 16384;
    const int m = wave >> 1, n = wave & 1;
    const int ch = cc * 32 + n * 16 + lr;
    const int brow = n * 16 + lr;
    const int arow = m * 16 + lr;
    f32x4 acc = {0.f, 0.f, 0.f, 0.f};
#pragma unroll
    for (int ks = 0; ks < 8; ++ks) {
      const int g = ks * 4 + lg;
      const bf16x8 a = *(const bf16x8*)(act + arow * 512 + GOFF(g, arow));
      const bf16x8 b = *(const bf16x8*)(wbp + brow * 512 + GOFF(g, brow));
      acc = MFMA(a, b, acc);
    }
#pragma unroll
    for (int r = 0; r < 4; ++r) {
      const int s = m * 16 + lg * 4 + r;
      g2[(size_t)(sb + s) * 256 + ch] = (__bf16)fast_tanh(acc[r] + bv2[cc]);
    }
    if (cc < 7) __syncthreads();
  }
}

// ---------------- diag_trunk: x -> tanh(Wd1) -> tanh(Wd2) -> Wdo -> xd ----------
__global__ __launch_bounds__(512, 2) void diag_trunk_kernel(
    const float* __restrict__ x, const __bf16* __restrict__ Wreg,
    const float* __restrict__ bd1, const float* __restrict__ bd2,
    const float* __restrict__ bdo, float* __restrict__ xd) {
  extern __shared__ char smem[];
  char* xa  = smem;            // 8 KB
  char* act = smem + 8192;     // 32 KB (h1, then h2)
  char* wb  = smem + 40960;    // 32 KB
  const char* Wc = (const char*)Wreg;

  const int tid = threadIdx.x;
  const int wave = tid >> 6, lane = tid & 63;
  const int lr = lane & 15, lg = lane >> 4;
  const int sb = blockIdx.x * 64;

  float bv1[2], bv2[8], bv3[2];
#pragma unroll
  for (int cc = 0; cc < 2; ++cc) bv1[cc] = bd1[cc * 128 + wave * 16 + lr];
#pragma unroll
  for (int cc = 0; cc < 8; ++cc) bv2[cc] = bd2[cc * 32 + (wave & 1) * 16 + lr];
#pragma unroll
  for (int cc = 0; cc < 2; ++cc) bv3[cc] = bdo[cc * 32 + (wave & 1) * 16 + lr];

  {
    const int s = tid >> 3, g = tid & 7;
    const bf16x8 v = cvt8(x + (size_t)(sb + s) * 64 + g * 8);
    *(bf16x8*)(xa + s * 128 + GOFF(g, s)) = v;
  }
  stage_chunk2(Wc, wb, 0, wave);
  __syncthreads();

#pragma unroll
  for (int cc = 0; cc < 2; ++cc) {
    stage_chunk2(Wc, wb, cc + 1, wave);
    const char* wbp = wb + (cc & 1) * 16384;
    const int brow = wave * 16 + lr;
    const bf16x8 b0 = *(const bf16x8*)(wbp + brow * 128 + GOFF(lg, brow));
    const bf16x8 b1 = *(const bf16x8*)(wbp + brow * 128 + GOFF(4 + lg, brow));
    const int ch = cc * 128 + brow;
#pragma unroll
    for (int m = 0; m < 4; ++m) {
      const int arow = m * 16 + lr;
      const bf16x8 a0 = *(const bf16x8*)(xa + arow * 128 + GOFF(lg, arow));
      const bf16x8 a1 = *(const bf16x8*)(xa + arow * 128 + GOFF(4 + lg, arow));
      f32x4 acc = {0.f, 0.f, 0.f, 0.f};
      acc = MFMA(a0, b0, acc);
      acc = MFMA(a1, b1, acc);
#pragma unroll
      for (int r = 0; r < 4; ++r) {
        const int s = m * 16 + lg * 4 + r;
        *(__bf16*)(act + s * 512 + GOFF(ch >> 3, s) + (ch & 7) * 2) =
            (__bf16)fast_tanh(acc[r] + bv1[cc]);
      }
    }
    __syncthreads();
  }

  f32x4 h2v[8];
#pragma unroll
  for (int cc = 0; cc < 8; ++cc) {
    const int c = cc + 2;
    if (c + 1 < 11) stage_chunk2(Wc, wb, c + 1, wave);
    const char* wbp = wb + (c & 1) * 16384;
    const int m = wave >> 1, n = wave & 1;
    const int brow = n * 16 + lr;
    const int arow = m * 16 + lr;
    f32x4 acc = {0.f, 0.f, 0.f, 0.f};
#pragma unroll
    for (int ks = 0; ks < 8; ++ks) {
      const int g = ks * 4 + lg;
      const bf16x8 a = *(const bf16x8*)(act + arow * 512 + GOFF(g, arow));
      const bf16x8 b = *(const bf16x8*)(wbp + brow * 512 + GOFF(g, brow));
      acc = MFMA(a, b, acc);
    }
#pragma unroll
    for (int r = 0; r < 4; ++r) h2v[cc][r] = fast_tanh(acc[r] + bv2[cc]);
    __syncthreads();
  }

  {
    const int m = wave >> 1, n = wave & 1;
#pragma unroll
    for (int cc = 0; cc < 8; ++cc) {
      const int ch = cc * 32 + n * 16 + lr;
#pragma unroll
      for (int r = 0; r < 4; ++r) {
        const int s = m * 16 + lg * 4 + r;
        *(__bf16*)(act + s * 512 + GOFF(ch >> 3, s) + (ch & 7) * 2) =
            (__bf16)h2v[cc][r];
      }
    }
  }
  stage_chunk2(Wc, wb, 11, wave);
  __syncthreads();

#pragma unroll
  for (int cc = 0; cc < 2; ++cc) {
    const char* wbp = wb + ((10 + cc) & 1) * 16384;
    const int m = wave >> 1, n = wave & 1;
    const int ch = cc * 32 + n * 16 + lr;
    const int brow = n * 16 + lr;
    const int arow = m * 16 + lr;
    f32x4 acc = {0.f, 0.f, 0.f, 0.f};
#pragma unroll
    for (int ks = 0; ks < 8; ++ks) {
      const int g = ks * 4 + lg;
      const bf16x8 a = *(const bf16x8*)(act + arow * 512 + GOFF(g, arow));
      const bf16x8 b = *(const bf16x8*)(wbp + brow * 512 + GOFF(g, brow));
      acc = MFMA(a, b, acc);
    }
#pragma unroll
    for (int r = 0; r < 4; ++r) {
      const int s = m * 16 + lg * 4 + r;
      xd[(size_t)(sb + s) * 64 + ch] = acc[r] + bv3[cc];
    }
  }
}

// ---------------- gemm_z: 128x128 tile, double-buffered 2-phase, 2 WG/CU --------
// LDS: A dbuf 2x16KB @0 | B dbuf 2x16KB @32768 | list @65536 (1KB).
// Loop: STAGE(buf^1, kt+1) issued FIRST, compute(buf), ONE barrier (drains vmcnt).
// Epilogue T (32KB) overlays the A dbuf after the final barrier.
#define GZ_LIST  65536
#define LIST_CAP 160
#define GZ_SMEM  (65536 + 1024)

__global__ __launch_bounds__(256, 2) void gemm_z_kernel(
    const __bf16* __restrict__ g2q, const __bf16* __restrict__ Woob,
    const float* __restrict__ boo, __bf16* __restrict__ zq, int bmper) {
  extern __shared__ char gsm[];
  const int tid = threadIdx.x;
  const int wave = tid >> 6, lane = tid & 63;
  const int lr = lane & 15, lg = lane >> 4;
  // XCD owns a contiguous bm range (g2 slice + Woob stay L2-resident)
  const int bm = (blockIdx.x & 7) * bmper + (blockIdx.x >> 7);
  const int bn = (blockIdx.x >> 3) & 15;
  const int wr = wave >> 1, wc = wave & 1;
  const int srl = lane >> 3, sch = lane & 7;

  int* lcnt = (int*)(gsm + GZ_LIST);
  unsigned* llist = (unsigned*)(gsm + GZ_LIST + 4);
  const int base = bn * 128;

#define GZSTAGE(BUF, KT)                                                        \
  {                                                                             \
    _Pragma("unroll")                                                           \
    for (int j = 0; j < 4; ++j) {                                               \
      const int row = wave * 32 + j * 8 + srl;                                  \
      const int ka = (KT) * 64 + ((sch ^ (row & 7)) << 3);                      \
      gload_lds16(g2q + (size_t)(bm * 128 + row) * 256 + ka,                    \
                  gsm + (BUF) * 16384 + wave * 4096 + j * 1024);                \
      gload_lds16(Woob + (size_t)(bn * 128 + row) * 256 + ka,                   \
                  gsm + 32768 + (BUF) * 16384 + wave * 4096 + j * 1024);        \
    }                                                                           \
  }

  // bias per fc
  float bvf[4];
#pragma unroll
  for (int fc = 0; fc < 4; ++fc) {
    const int col = base + wc * 64 + fc * 16 + lr;
    bvf[fc] = (col < OFFD) ? boo[col] : 0.f;
  }

  f32x4 acc[4][4];
#pragma unroll
  for (int i = 0; i < 4; ++i)
#pragma unroll
    for (int j = 0; j < 4; ++j) acc[i][j] = (f32x4){0.f, 0.f, 0.f, 0.f};

  GZSTAGE(0, 0)
  if (tid == 0) *lcnt = 0;
  __syncthreads();   // certifies stage(0) + lcnt

  // compacted dest-granule list for this bn window (runs once, off critical path)
  for (int gi = tid; gi < 528; gi += 256) {
    const int off0 = gi * 4;
    int i = (int)((1.f + sqrtf((float)(8 * off0 + 1))) * 0.5f);
    if (i > 63) i = 63;
    if (i < 1) i = 1;
    while (i > 1 && rs_of(i) > off0) --i;
    while (i < 63 && rs_of(i + 1) <= off0) ++i;
    const int j0 = off0 - rs_of(i);
    int nv = i - j0;
    if (nv > 4) nv = 4;
    const int c0 = ((i * (i - 1)) >> 1) + j0;
    const int last = c0 + nv - 1;
    if (last >= base && c0 <= base + 127) {
      const int idx = atomicAdd(lcnt, 1);
      if (idx < LIST_CAP)
        llist[idx] = ((unsigned)gi << 16) | ((unsigned)i << 9) |
                     ((unsigned)j0 << 3) | (unsigned)nv;
    }
  }

#pragma unroll
  for (int kt = 0; kt < 4; ++kt) {
    const int buf = kt & 1;
    if (kt < 3) GZSTAGE(buf ^ 1, kt + 1)     // prefetch overlaps compute(kt)
    const char* Ab = gsm + buf * 16384;
    const char* Bb = gsm + 32768 + buf * 16384;
#pragma unroll
    for (int ks = 0; ks < 2; ++ks) {
      bf16x8 af[4], bfr[4];
#pragma unroll
      for (int f = 0; f < 4; ++f) {
        const int ra = wr * 64 + f * 16 + lr;
        af[f] = *(const bf16x8*)(Ab + ra * 128 + GOFF(ks * 4 + lg, ra));
        const int rb = wc * 64 + f * 16 + lr;
        bfr[f] = *(const bf16x8*)(Bb + rb * 128 + GOFF(ks * 4 + lg, rb));
      }
#pragma unroll
      for (int fr = 0; fr < 4; ++fr)
#pragma unroll
        for (int fc = 0; fc < 4; ++fc)
          acc[fr][fc] = MFMA(af[fr], bfr[fc], acc[fr][fc]);
    }
    __syncthreads();   // drains vmcnt (prefetch landed) + syncs buffer swap
  }

  // ---- epilogue: dump C-tile to LDS T (32KB over A dbuf), 16B stores ----
  {
    unsigned long long* Tq = (unsigned long long*)gsm;
#pragma unroll
    for (int fr = 0; fr < 4; ++fr) {
      const int rgrp = wr * 16 + fr * 4 + lg;   // 4-row granule (0..31)
#pragma unroll
      for (int fc = 0; fc < 4; ++fc) {
        const int ncol = wc * 64 + fc * 16 + lr;  // local col (0..127)
        const unsigned long long v =
            (unsigned long long)bfbits(acc[fr][fc][0] + bvf[fc]) |
            ((unsigned long long)bfbits(acc[fr][fc][1] + bvf[fc]) << 16) |
            ((unsigned long long)bfbits(acc[fr][fc][2] + bvf[fc]) << 32) |
            ((unsigned long long)bfbits(acc[fr][fc][3] + bvf[fc]) << 48);
        Tq[ncol * 32 + (rgrp ^ (ncol & 7))] = v;
      }
    }
  }
  __syncthreads();

  {
    const unsigned* Tw = (const unsigned*)gsm;
    int nl = *lcnt;
    if (nl > LIST_CAP) nl = LIST_CAP;
    const int p = tid >> 2;                  // local pair 0..63
    const int grp = bm * 4 + (p >> 4);
    __bf16* zdst = zq + (size_t)grp * GRP_UNITS + (p & 15) * 4224;
    for (int li = (tid & 3); li < nl; li += 4) {
      const unsigned e = llist[li];
      const int gi = e >> 16;
      const int i = (e >> 9) & 63;
      const int j0 = (e >> 3) & 63;
      const int nv = e & 7;
      const int c0 = ((i * (i - 1)) >> 1) + j0;
      const int lc0 = c0 - base;
      unsigned u[4];
#pragma unroll
      for (int d = 0; d < 4; ++d) {
        const int lc = lc0 + d;
        const bool valid = (d < nv) && (lc >= 0) && (lc <= 127);
        u[d] = valid
                   ? Tw[lc * 64 + (((p >> 1) ^ (lc & 7)) << 1) + (p & 1)]
                   : 0u;
      }
      const bool full = (lc0 >= 0) && (lc0 + nv - 1 <= 127);
      if (full) {
        uint4 w;
        w.x = u[0]; w.y = u[1]; w.z = u[2]; w.w = u[3];
        *(uint4*)(zdst + (size_t)gi * 8) = w;
      } else {
        const bool ownpad = (lc0 + nv - 1 >= 0) && (lc0 + nv - 1 <= 127);
#pragma unroll
        for (int d = 0; d < 4; ++d) {
          const int lc = lc0 + d;
          const bool own =
              (d < nv) ? ((lc >= 0) && (lc <= 127)) : ownpad;
          if (own) *(unsigned*)(zdst + (size_t)gi * 8 + d * 2) = u[d];
        }
      }
    }
  }
}

// ---------------- apply: 512 thr, 16 samples (half group) -> 2 WG/CU ------------
#define APPLY_SMEM (8 * 8448 + 4096)
__global__ __launch_bounds__(512, 2) void apply_kernel(
    const __bf16* __restrict__ zq, const float* __restrict__ xd,
    const float* __restrict__ x0, float* __restrict__ out, int s0base) {
  extern __shared__ char smem[];
  __bf16* ztb = (__bf16*)smem;                 // 8 pairs x 4224 units
  float* ys2 = (float*)(smem + 8 * 8448);      // [8][128]

  const int tid = threadIdx.x;
  const int wave = tid >> 6, lane = tid & 63;
  const int blk = blockIdx.x;
  const int sb = s0base + blk * 16;
  const int s0 = wave * 2, s1 = s0 + 1;

  const float x0vA = x0[(size_t)(sb + s0) * 64 + lane];
  const float x0vB = x0[(size_t)(sb + s1) * 64 + lane];
  const float xdA = xd[(size_t)(sb + s0) * 64 + lane];
  const float xdB = xd[(size_t)(sb + s1) * 64 + lane];

  {
    const char* src = (const char*)zq + (size_t)(blk >> 1) * GRP_BYTES +
                      ((blk & 1) * 8 + wave) * 8448;
    char* dst = smem + wave * 8448;
#pragma unroll
    for (int j = 0; j < 8; ++j)
      gload_lds16(src + j * 1024 + lane * 16, dst + j * 1024);
    if (lane < 16) gload_lds16(src + 8192 + lane * 16, dst + 8192);
  }
  asm volatile("s_waitcnt vmcnt(0)" ::: "memory");
  SB0();

  const __bf16* zpair = ztb + wave * 4224;

  // pass 1: y_j = xd_j x0_j + sum_{k>j} z[k][j] x0_k
  float yA = xdA * x0vA, yB = xdB * x0vB;
  int rs = 0;
#pragma unroll
  for (int k = 1; k < 64; ++k) {
    const unsigned w = *(const unsigned*)(zpair + (rs + lane) * 2);
    const float xkA = lane_bcast(x0vA, k);
    const float xkB = lane_bcast(x0vB, k);
    const bool mvalid = lane < k;
    yA += mvalid ? bf_lo(w) * xkA : 0.f;
    yB += mvalid ? bf_hi(w) * xkB : 0.f;
    rs += (k + 3) & ~3;
  }

  float* yp = ys2 + wave * 128;
  *(float2*)(yp + lane * 2) = make_float2(yA, yB);
  asm volatile("s_waitcnt lgkmcnt(0)" ::: "memory");
  SB0();

  // pass 2: D_i = xd_i y_i + sum_{j<i} z[i][j] y_j  (zero pads absorb masks)
  float DA = xdA * yA, DB = xdB * yB;
  float dA1 = 0.f, dB1 = 0.f;
  {
    const int r3 = lane & 3;
    const int rsi = ((lane * (lane - 1)) >> 1) + 6 * (lane >> 2) +
                    ((r3 == 2) ? 3 : (r3 == 3) ? 5 : 0);
    const int cmax = (lane + 3) >> 2;
    const __bf16* zrow = zpair + rsi * 2;
#pragma unroll 4
    for (int c = 0; c < cmax; ++c) {
      const uint4 w = *(const uint4*)(zrow + c * 8);
      const float4 u0 = *(const float4*)(yp + c * 8);
      const float4 u1 = *(const float4*)(yp + c * 8 + 4);
      DA += bf_lo(w.x) * u0.x + bf_lo(w.z) * u1.x;
      dA1 += bf_lo(w.y) * u0.z + bf_lo(w.w) * u1.z;
      DB += bf_hi(w.x) * u0.y + bf_hi(w.z) * u1.y;
      dB1 += bf_hi(w.y) * u0.w + bf_hi(w.w) * u1.w;
    }
  }
  out[(size_t)(sb + s0) * 64 + lane] = DA + dA1;
  out[(size_t)(sb + s1) * 64 + lane] = DB + dB1;
}

// ---------------- launch ----------------
extern "C" void kernel_launch(void* const* d_in, const int* in_sizes, int n_in,
                              void* d_out, int out_size, void* d_ws, size_t ws_size,
                              hipStream_t stream) {
  const float* x   = (const float*)d_in[0];
  const float* Wd1 = (const float*)d_in[1];
  const float* bd1 = (const float*)d_in[2];
  const float* Wd2 = (const float*)d_in[3];
  const float* bd2 = (const float*)d_in[4];
  const float* Wdo = (const float*)d_in[5];
  const float* bdo = (const float*)d_in[6];
  const float* Wo1 = (const float*)d_in[7];
  const float* bo1 = (const float*)d_in[8];
  const float* Wo2 = (const float*)d_in[9];
  const float* bo2 = (const float*)d_in[10];
  const float* Woo = (const float*)d_in[11];
  const float* boo = (const float*)d_in[12];
  float* out = (float*)d_out;

  char* ws = (char*)d_ws;
  // Wcat (bf16 elems): Wo1@0 | Wo2@16384 | Wd1@81920 | Wd2@98304 | Wdo@163840
  __bf16* Wcat = (__bf16*)(ws + 0);          //   360448 B
  __bf16* Woob = (__bf16*)(ws + 360448);     //  1048576 B (zero-padded rows)
  __bf16* g2   = (__bf16*)(ws + 1409024);    // 16777216 B
  float*  xdp  = (float*)(ws + 18186240);    //  8388608 B
  const size_t zoff = 26574848;
  __bf16* zq   = (__bf16*)(ws + zoff);       // z slice buffer

  const size_t zcap = (ws_size > zoff) ? (ws_size - zoff) : 0;
  int nslices = 4;
  if (zcap >= (size_t)1024 * GRP_BYTES) nslices = 1;
  else if (zcap >= (size_t)512 * GRP_BYTES) nslices = 2;
  const int QSs = B_TOT / nslices;
  const int nbm = QSs / 128;       // 128-sample tiles
  const int bmper = nbm >> 3;

  cast_all_kernel<<<512, 256, 0, stream>>>(
      Wo1, Wcat, HDIM * NDIM,
      Wo2, Wcat + 16384, HDIM * HDIM,
      Wd1, Wcat + 81920, HDIM * NDIM,
      Wd2, Wcat + 98304, HDIM * HDIM,
      Wdo, Wcat + 163840, NDIM * HDIM,
      Woo, Woob, OFFD * HDIM,
      Woob + OFFD * HDIM, 32 * HDIM);

  hipFuncSetAttribute((const void*)off_trunk_kernel,
                      hipFuncAttributeMaxDynamicSharedMemorySize, TRK_SMEM);
  hipFuncSetAttribute((const void*)diag_trunk_kernel,
                      hipFuncAttributeMaxDynamicSharedMemorySize, TRK_SMEM);
  off_trunk_kernel<<<B_TOT / 64, 512, TRK_SMEM, stream>>>(
      x, Wcat, bo1, bo2, g2);
  diag_trunk_kernel<<<B_TOT / 64, 512, TRK_SMEM, stream>>>(
      x, Wcat + 81920, bd1, bd2, bdo, xdp);

  hipFuncSetAttribute((const void*)gemm_z_kernel,
                      hipFuncAttributeMaxDynamicSharedMemorySize, GZ_SMEM);
  hipFuncSetAttribute((const void*)apply_kernel,
                      hipFuncAttributeMaxDynamicSharedMemorySize, APPLY_SMEM);
  for (int s = 0; s < nslices; ++s) {
    gemm_z_kernel<<<nbm * 16, 256, GZ_SMEM, stream>>>(
        g2 + (size_t)s * QSs * HDIM, Woob, boo, zq, bmper);
    apply_kernel<<<QSs / 16, 512, APPLY_SMEM, stream>>>(zq, xdp, x, out, s * QSs);
  }
}

// Round 19
// 152.642 us; speedup vs baseline: 1.0683x; 1.0683x over previous
//
#include <hip/hip_runtime.h>
#include <math.h>

// Damping: B=32768, N=64, H=256, OFF=2016
//   diag: x -> tanh(Wd1) -> tanh(Wd2) -> Wdo   (64 per sample)
//   off : x -> tanh(Wo1) -> tanh(Wo2) -> Woo   (2016 per sample, strict lower tri)
//   out = L (L^T x0), L diag = xd, L[i][j](j<i) = z[i(i-1)/2+j]
//
// z path v4: gemm_z (128x128 tile, 4 WG/CU) -> PLAIN row-major z[s][2048] in HBM
// (col = packed tri index, pad cols zero) -> apply (linear stage + 2 passes).

#define B_TOT 32768
#define NDIM  64
#define HDIM  256
#define OFFD  2016
#define ZCOLS 2048                 // padded row length (bf16)
#define ZROWB 4096                 // bytes per z row

typedef __bf16 bf16x8 __attribute__((ext_vector_type(8)));
typedef float  f32x4  __attribute__((ext_vector_type(4)));

__device__ __forceinline__ float fast_tanh(float x) {
  float e = __expf(2.f * x);
  return 1.f - 2.f * __builtin_amdgcn_rcpf(e + 1.f);
}
__device__ __forceinline__ float lane_bcast(float v, int l) {
  return __uint_as_float(__builtin_amdgcn_readlane(__float_as_uint(v), l));
}
__device__ __forceinline__ float bf_lo(unsigned w) { return __uint_as_float(w << 16); }
__device__ __forceinline__ float bf_hi(unsigned w) { return __uint_as_float(w & 0xffff0000u); }

__device__ __forceinline__ void gload_lds16(const void* g, void* l) {
  __builtin_amdgcn_global_load_lds(
      (const __attribute__((address_space(1))) unsigned*)g,
      (__attribute__((address_space(3))) unsigned*)l, 16, 0, 0);
}

#define MFMA(A, B, C) __builtin_amdgcn_mfma_f32_16x16x32_bf16((A), (B), (C), 0, 0, 0)
#define SB0() __builtin_amdgcn_sched_barrier(0)
// XOR-swizzled 16B-granule byte offset within a row (low 3 bits of granule)
#define GOFF(g, row) (((((g) & ~7) | (((g) & 7) ^ ((row) & 7)))) << 4)

// ---------------- weight cast (f32 -> bf16) + Woob pad zero-fill ----------------
__device__ __forceinline__ void cast_range(const float* __restrict__ s,
                                           __bf16* __restrict__ d, int n) {
  int i = blockIdx.x * blockDim.x + threadIdx.x;
  const int stride = gridDim.x * blockDim.x;
  for (; i < n; i += stride) d[i] = (__bf16)s[i];
}
__global__ __launch_bounds__(256) void cast_all_kernel(
    const float* s0, __bf16* d0, int n0, const float* s1, __bf16* d1, int n1,
    const float* s2, __bf16* d2, int n2, const float* s3, __bf16* d3, int n3,
    const float* s4, __bf16* d4, int n4, const float* s5, __bf16* d5, int n5,
    __bf16* d6, int n6) {
  cast_range(s0, d0, n0); cast_range(s1, d1, n1); cast_range(s2, d2, n2);
  cast_range(s3, d3, n3); cast_range(s4, d4, n4); cast_range(s5, d5, n5);
  int i = blockIdx.x * blockDim.x + threadIdx.x;
  const int stride = gridDim.x * blockDim.x;
  for (; i < n6; i += stride) d6[i] = (__bf16)0.f;
}

__device__ __forceinline__ bf16x8 cvt8(const float* __restrict__ p) {
  const float4 u = *(const float4*)p;
  const float4 v = *(const float4*)(p + 4);
  bf16x8 r;
  r[0] = (__bf16)u.x; r[1] = (__bf16)u.y; r[2] = (__bf16)u.z; r[3] = (__bf16)u.w;
  r[4] = (__bf16)v.x; r[5] = (__bf16)v.y; r[6] = (__bf16)v.z; r[7] = (__bf16)v.w;
  return r;
}

// ---------------- shared trunk machinery: 64 samples/WG, 72KB LDS, 2 WG/CU ------
#define TRK_SMEM (8192 + 32768 + 32768)

// stage one 16KB weight chunk; rows are 128B if c<2 else 512B
__device__ __forceinline__ void stage_chunk2(const char* wreg, char* wb,
                                             int c, int wave) {
  const char* base = wreg + (size_t)c * 16384;
  char* dst = wb + (c & 1) * 16384;
  const int lane = threadIdx.x & 63;
  const int s0 = wave * 64 + lane;
  const int s1 = s0 + 512;
  if (c < 2) {  // 128-byte rows (8 granules)
    const int r0 = s0 >> 3, q0 = (s0 & 7) ^ (r0 & 7);
    gload_lds16(base + r0 * 128 + (q0 << 4), dst + wave * 1024);
    const int r1 = s1 >> 3, q1 = (s1 & 7) ^ (r1 & 7);
    gload_lds16(base + r1 * 128 + (q1 << 4), dst + (wave + 8) * 1024);
  } else {      // 512-byte rows (32 granules)
    const int r0 = s0 >> 5, g0 = s0 & 31;
    const int q0 = (g0 & 24) | ((g0 & 7) ^ (r0 & 7));
    gload_lds16(base + r0 * 512 + (q0 << 4), dst + wave * 1024);
    const int r1 = s1 >> 5, g1 = s1 & 31;
    const int q1 = (g1 & 24) | ((g1 & 7) ^ (r1 & 7));
    gload_lds16(base + r1 * 512 + (q1 << 4), dst + (wave + 8) * 1024);
  }
}

// ---------------- off_trunk: x -> tanh(Wo1) -> tanh(Wo2) -> g2 ------------------
__global__ __launch_bounds__(512, 2) void off_trunk_kernel(
    const float* __restrict__ x, const __bf16* __restrict__ Wreg,
    const float* __restrict__ bo1, const float* __restrict__ bo2,
    __bf16* __restrict__ g2) {
  extern __shared__ char smem[];
  char* xa  = smem;            // 8 KB
  char* act = smem + 8192;     // 32 KB (g1)
  char* wb  = smem + 40960;    // 32 KB
  const char* Wc = (const char*)Wreg;

  const int tid = threadIdx.x;
  const int wave = tid >> 6, lane = tid & 63;
  const int lr = lane & 15, lg = lane >> 4;
  const int sb = blockIdx.x * 64;

  float bv1[2], bv2[8];
#pragma unroll
  for (int cc = 0; cc < 2; ++cc) bv1[cc] = bo1[cc * 128 + wave * 16 + lr];
#pragma unroll
  for (int cc = 0; cc < 8; ++cc) bv2[cc] = bo2[cc * 32 + (wave & 1) * 16 + lr];

  {
    const int s = tid >> 3, g = tid & 7;
    const bf16x8 v = cvt8(x + (size_t)(sb + s) * 64 + g * 8);
    *(bf16x8*)(xa + s * 128 + GOFF(g, s)) = v;
  }
  stage_chunk2(Wc, wb, 0, wave);
  __syncthreads();

#pragma unroll
  for (int cc = 0; cc < 2; ++cc) {
    stage_chunk2(Wc, wb, cc + 1, wave);
    const char* wbp = wb + (cc & 1) * 16384;
    const int brow = wave * 16 + lr;
    const bf16x8 b0 = *(const bf16x8*)(wbp + brow * 128 + GOFF(lg, brow));
    const bf16x8 b1 = *(const bf16x8*)(wbp + brow * 128 + GOFF(4 + lg, brow));
    const int ch = cc * 128 + brow;
#pragma unroll
    for (int m = 0; m < 4; ++m) {
      const int arow = m * 16 + lr;
      const bf16x8 a0 = *(const bf16x8*)(xa + arow * 128 + GOFF(lg, arow));
      const bf16x8 a1 = *(const bf16x8*)(xa + arow * 128 + GOFF(4 + lg, arow));
      f32x4 acc = {0.f, 0.f, 0.f, 0.f};
      acc = MFMA(a0, b0, acc);
      acc = MFMA(a1, b1, acc);
#pragma unroll
      for (int r = 0; r < 4; ++r) {
        const int s = m * 16 + lg * 4 + r;
        *(__bf16*)(act + s * 512 + GOFF(ch >> 3, s) + (ch & 7) * 2) =
            (__bf16)fast_tanh(acc[r] + bv1[cc]);
      }
    }
    __syncthreads();
  }

#pragma unroll
  for (int cc = 0; cc < 8; ++cc) {
    const int c = cc + 2;
    if (c + 1 < 10) stage_chunk2(Wc, wb, c + 1, wave);
    const char* wbp = wb + (c & 1) * 16384;
    const int m = wave >> 1, n = wave & 1;
    const int ch = cc * 32 + n * 16 + lr;
    const int brow = n * 16 + lr;
    const int arow = m * 16 + lr;
    f32x4 acc = {0.f, 0.f, 0.f, 0.f};
#pragma unroll
    for (int ks = 0; ks < 8; ++ks) {
      const int g = ks * 4 + lg;
      const bf16x8 a = *(const bf16x8*)(act + arow * 512 + GOFF(g, arow));
      const bf16x8 b = *(const bf16x8*)(wbp + brow * 512 + GOFF(g, brow));
      acc = MFMA(a, b, acc);
    }
#pragma unroll
    for (int r = 0; r < 4; ++r) {
      const int s = m * 16 + lg * 4 + r;
      g2[(size_t)(sb + s) * 256 + ch] = (__bf16)fast_tanh(acc[r] + bv2[cc]);
    }
    if (cc < 7) __syncthreads();
  }
}

// ---------------- diag_trunk: x -> tanh(Wd1) -> tanh(Wd2) -> Wdo -> xd ----------
__global__ __launch_bounds__(512, 2) void diag_trunk_kernel(
    const float* __restrict__ x, const __bf16* __restrict__ Wreg,
    const float* __restrict__ bd1, const float* __restrict__ bd2,
    const float* __restrict__ bdo, float* __restrict__ xd) {
  extern __shared__ char smem[];
  char* xa  = smem;            // 8 KB
  char* act = smem + 8192;     // 32 KB (h1, then h2)
  char* wb  = smem + 40960;    // 32 KB
  const char* Wc = (const char*)Wreg;

  const int tid = threadIdx.x;
  const int wave = tid >> 6, lane = tid & 63;
  const int lr = lane & 15, lg = lane >> 4;
  const int sb = blockIdx.x * 64;

  float bv1[2], bv2[8], bv3[2];
#pragma unroll
  for (int cc = 0; cc < 2; ++cc) bv1[cc] = bd1[cc * 128 + wave * 16 + lr];
#pragma unroll
  for (int cc = 0; cc < 8; ++cc) bv2[cc] = bd2[cc * 32 + (wave & 1) * 16 + lr];
#pragma unroll
  for (int cc = 0; cc < 2; ++cc) bv3[cc] = bdo[cc * 32 + (wave & 1) * 16 + lr];

  {
    const int s = tid >> 3, g = tid & 7;
    const bf16x8 v = cvt8(x + (size_t)(sb + s) * 64 + g * 8);
    *(bf16x8*)(xa + s * 128 + GOFF(g, s)) = v;
  }
  stage_chunk2(Wc, wb, 0, wave);
  __syncthreads();

#pragma unroll
  for (int cc = 0; cc < 2; ++cc) {
    stage_chunk2(Wc, wb, cc + 1, wave);
    const char* wbp = wb + (cc & 1) * 16384;
    const int brow = wave * 16 + lr;
    const bf16x8 b0 = *(const bf16x8*)(wbp + brow * 128 + GOFF(lg, brow));
    const bf16x8 b1 = *(const bf16x8*)(wbp + brow * 128 + GOFF(4 + lg, brow));
    const int ch = cc * 128 + brow;
#pragma unroll
    for (int m = 0; m < 4; ++m) {
      const int arow = m * 16 + lr;
      const bf16x8 a0 = *(const bf16x8*)(xa + arow * 128 + GOFF(lg, arow));
      const bf16x8 a1 = *(const bf16x8*)(xa + arow * 128 + GOFF(4 + lg, arow));
      f32x4 acc = {0.f, 0.f, 0.f, 0.f};
      acc = MFMA(a0, b0, acc);
      acc = MFMA(a1, b1, acc);
#pragma unroll
      for (int r = 0; r < 4; ++r) {
        const int s = m * 16 + lg * 4 + r;
        *(__bf16*)(act + s * 512 + GOFF(ch >> 3, s) + (ch & 7) * 2) =
            (__bf16)fast_tanh(acc[r] + bv1[cc]);
      }
    }
    __syncthreads();
  }

  f32x4 h2v[8];
#pragma unroll
  for (int cc = 0; cc < 8; ++cc) {
    const int c = cc + 2;
    if (c + 1 < 11) stage_chunk2(Wc, wb, c + 1, wave);
    const char* wbp = wb + (c & 1) * 16384;
    const int m = wave >> 1, n = wave & 1;
    const int brow = n * 16 + lr;
    const int arow = m * 16 + lr;
    f32x4 acc = {0.f, 0.f, 0.f, 0.f};
#pragma unroll
    for (int ks = 0; ks < 8; ++ks) {
      const int g = ks * 4 + lg;
      const bf16x8 a = *(const bf16x8*)(act + arow * 512 + GOFF(g, arow));
      const bf16x8 b = *(const bf16x8*)(wbp + brow * 512 + GOFF(g, brow));
      acc = MFMA(a, b, acc);
    }
#pragma unroll
    for (int r = 0; r < 4; ++r) h2v[cc][r] = fast_tanh(acc[r] + bv2[cc]);
    __syncthreads();
  }

  {
    const int m = wave >> 1, n = wave & 1;
#pragma unroll
    for (int cc = 0; cc < 8; ++cc) {
      const int ch = cc * 32 + n * 16 + lr;
#pragma unroll
      for (int r = 0; r < 4; ++r) {
        const int s = m * 16 + lg * 4 + r;
        *(__bf16*)(act + s * 512 + GOFF(ch >> 3, s) + (ch & 7) * 2) =
            (__bf16)h2v[cc][r];
      }
    }
  }
  stage_chunk2(Wc, wb, 11, wave);
  __syncthreads();

#pragma unroll
  for (int cc = 0; cc < 2; ++cc) {
    const char* wbp = wb + ((10 + cc) & 1) * 16384;
    const int m = wave >> 1, n = wave & 1;
    const int ch = cc * 32 + n * 16 + lr;
    const int brow = n * 16 + lr;
    const int arow = m * 16 + lr;
    f32x4 acc = {0.f, 0.f, 0.f, 0.f};
#pragma unroll
    for (int ks = 0; ks < 8; ++ks) {
      const int g = ks * 4 + lg;
      const bf16x8 a = *(const bf16x8*)(act + arow * 512 + GOFF(g, arow));
      const bf16x8 b = *(const bf16x8*)(wbp + brow * 512 + GOFF(g, brow));
      acc = MFMA(a, b, acc);
    }
#pragma unroll
    for (int r = 0; r < 4; ++r) {
      const int s = m * 16 + lg * 4 + r;
      xd[(size_t)(sb + s) * 64 + ch] = acc[r] + bv3[cc];
    }
  }
}

// ---------------- gemm_z v4: 128x128 tile, 4 waves, 4 WG/CU, plain-row output ---
// LDS: A 16KB | B 16KB.  Epilogue: direct store_short into z[s][2048] (dense
// per-WG region; L2 merges the 32B lane-group segments).
#define GZ_SMEM 32768

__global__ __launch_bounds__(256, 4) void gemm_z_kernel(
    const __bf16* __restrict__ g2q, const __bf16* __restrict__ Woob,
    const float* __restrict__ boo, __bf16* __restrict__ zq, int bmper) {
  extern __shared__ char gsm[];
  const int tid = threadIdx.x;
  const int wave = tid >> 6, lane = tid & 63;
  const int lr = lane & 15, lg = lane >> 4;
  // XCD owns a contiguous bm range (g2 slice + Woob stay L2-resident)
  const int bm = (blockIdx.x & 7) * bmper + (blockIdx.x >> 7);
  const int bn = (blockIdx.x >> 3) & 15;
  const int wr = wave >> 1, wc = wave & 1;
  const int srl = lane >> 3, sch = lane & 7;

#define GZSTAGE(KT)                                                             \
  {                                                                             \
    _Pragma("unroll")                                                           \
    for (int j = 0; j < 4; ++j) {                                               \
      const int row = wave * 32 + j * 8 + srl;                                  \
      const int ka = (KT) * 64 + ((sch ^ (row & 7)) << 3);                      \
      gload_lds16(g2q + (size_t)(bm * 128 + row) * 256 + ka,                    \
                  gsm + wave * 4096 + j * 1024);                                \
      gload_lds16(Woob + (size_t)(bn * 128 + row) * 256 + ka,                   \
                  gsm + 16384 + wave * 4096 + j * 1024);                        \
    }                                                                           \
  }

  // bias per fc (boo reads; col>=OFFD -> 0, matching zero Woob pad rows)
  float bvf[4];
#pragma unroll
  for (int fc = 0; fc < 4; ++fc) {
    const int col = bn * 128 + wc * 64 + fc * 16 + lr;
    bvf[fc] = (col < OFFD) ? boo[col] : 0.f;
  }

  f32x4 acc[4][4];
#pragma unroll
  for (int i = 0; i < 4; ++i)
#pragma unroll
    for (int j = 0; j < 4; ++j) acc[i][j] = (f32x4){0.f, 0.f, 0.f, 0.f};

  GZSTAGE(0)
  __syncthreads();

#pragma unroll
  for (int kt = 0; kt < 4; ++kt) {
    if (kt > 0) {
      GZSTAGE(kt)
      __syncthreads();
    }
    const char* Ab = gsm;
    const char* Bb = gsm + 16384;
#pragma unroll
    for (int ks = 0; ks < 2; ++ks) {
      bf16x8 af[4], bfr[4];
#pragma unroll
      for (int f = 0; f < 4; ++f) {
        const int ra = wr * 64 + f * 16 + lr;
        af[f] = *(const bf16x8*)(Ab + ra * 128 + GOFF(ks * 4 + lg, ra));
        const int rb = wc * 64 + f * 16 + lr;
        bfr[f] = *(const bf16x8*)(Bb + rb * 128 + GOFF(ks * 4 + lg, rb));
      }
#pragma unroll
      for (int fr = 0; fr < 4; ++fr)
#pragma unroll
        for (int fc = 0; fc < 4; ++fc)
          acc[fr][fc] = MFMA(af[fr], bfr[fc], acc[fr][fc]);
    }
    if (kt < 3) __syncthreads();
  }

  // epilogue: direct scalar stores into plain z[s][2048]
#pragma unroll
  for (int fr = 0; fr < 4; ++fr) {
    const int row0 = bm * 128 + wr * 64 + fr * 16 + lg * 4;
#pragma unroll
    for (int fc = 0; fc < 4; ++fc) {
      const int col = bn * 128 + wc * 64 + fc * 16 + lr;
      __bf16* p = zq + (size_t)row0 * ZCOLS + col;
#pragma unroll
      for (int r = 0; r < 4; ++r)
        p[(size_t)r * ZCOLS] = (__bf16)(acc[fr][fc][r] + bvf[fc]);
    }
  }
}

// ---------------- apply v4: 512 thr, 16 samples, plain-row stage, 2 WG/CU -------
// LDS: zs 16 x 4096B = 64KB | ys 8 x 128 f32 = 4KB
#define APPLY_SMEM (65536 + 4096)
__global__ __launch_bounds__(512, 2) void apply_kernel(
    const __bf16* __restrict__ zq, const float* __restrict__ xd,
    const float* __restrict__ x0, float* __restrict__ out, int s0base) {
  extern __shared__ char smem[];
  float* ys2 = (float*)(smem + 65536);

  const int tid = threadIdx.x;
  const int wave = tid >> 6, lane = tid & 63;
  const int sb = s0base + blockIdx.x * 16;
  const int s0 = wave * 2, s1 = s0 + 1;

  const float x0vA = x0[(size_t)(sb + s0) * 64 + lane];
  const float x0vB = x0[(size_t)(sb + s1) * 64 + lane];
  const float xdA = xd[(size_t)(sb + s0) * 64 + lane];
  const float xdB = xd[(size_t)(sb + s1) * 64 + lane];

  // linear stage: 2 sample rows (4096 B each) per wave
  {
    const char* srcA = (const char*)(zq + (size_t)(sb + s0) * ZCOLS);
    char* dstA = smem + wave * 8192;
#pragma unroll
    for (int j = 0; j < 4; ++j) {
      gload_lds16(srcA + j * 1024 + lane * 16, dstA + j * 1024);
      gload_lds16(srcA + ZROWB + j * 1024 + lane * 16, dstA + 4096 + j * 1024);
    }
  }
  asm volatile("s_waitcnt vmcnt(0)" ::: "memory");
  SB0();

  const __bf16* zsA = (const __bf16*)(smem + wave * 8192);
  const __bf16* zsB = zsA + ZCOLS;

  // pass 1: y_j = xd_j x0_j + sum_{k>j} z[k(k-1)/2 + j] x0_k   (j = lane)
  float yA = xdA * x0vA, yB = xdB * x0vB;
  int rs = 0;
#pragma unroll
  for (int k = 1; k < 64; ++k) {
    const float zA = (float)zsA[rs + lane];
    const float zB = (float)zsB[rs + lane];
    const float xkA = lane_bcast(x0vA, k);
    const float xkB = lane_bcast(x0vB, k);
    const bool mv = lane < k;
    yA += mv ? zA * xkA : 0.f;
    yB += mv ? zB * xkB : 0.f;
    rs += k;
  }

  float* ypA = ys2 + wave * 128;
  float* ypB = ypA + 64;
  ypA[lane] = yA;
  ypB[lane] = yB;
  asm volatile("s_waitcnt lgkmcnt(0)" ::: "memory");
  SB0();

  // pass 2: D_i = xd_i y_i + sum_{j<i} z[i(i-1)/2 + j] y_j   (i = lane; cols contiguous)
  float DA = xdA * yA, DB = xdB * yB;
  {
    const int base = (lane * (lane - 1)) >> 1;
    const int nf = lane >> 3;          // full 8-col granules
    const int t = lane & 7;            // tail cols
    const char* zrA = (const char*)zsA + base * 2;
    const char* zrB = (const char*)zsB + base * 2;
    for (int c = 0; c < nf; ++c) {
      const uint4 wA = *(const uint4*)(zrA + c * 16);
      const uint4 wB = *(const uint4*)(zrB + c * 16);
      const float4 u0 = *(const float4*)(ypA + c * 8);
      const float4 u1 = *(const float4*)(ypA + c * 8 + 4);
      const float4 v0 = *(const float4*)(ypB + c * 8);
      const float4 v1 = *(const float4*)(ypB + c * 8 + 4);
      DA += bf_lo(wA.x) * u0.x + bf_hi(wA.x) * u0.y + bf_lo(wA.y) * u0.z +
            bf_hi(wA.y) * u0.w + bf_lo(wA.z) * u1.x + bf_hi(wA.z) * u1.y +
            bf_lo(wA.w) * u1.z + bf_hi(wA.w) * u1.w;
      DB += bf_lo(wB.x) * v0.x + bf_hi(wB.x) * v0.y + bf_lo(wB.y) * v0.z +
            bf_hi(wB.y) * v0.w + bf_lo(wB.z) * v1.x + bf_hi(wB.z) * v1.y +
            bf_lo(wB.w) * v1.z + bf_hi(wB.w) * v1.w;
    }
    if (t) {  // tail granule (read stays within padded row; mask invalid cols)
      const uint4 wA = *(const uint4*)(zrA + nf * 16);
      const uint4 wB = *(const uint4*)(zrB + nf * 16);
      const float4 u0 = *(const float4*)(ypA + nf * 8);
      const float4 u1 = *(const float4*)(ypA + nf * 8 + 4);
      const float4 v0 = *(const float4*)(ypB + nf * 8);
      const float4 v1 = *(const float4*)(ypB + nf * 8 + 4);
      DA += ((0 < t) ? bf_lo(wA.x) * u0.x : 0.f) + ((1 < t) ? bf_hi(wA.x) * u0.y : 0.f) +
            ((2 < t) ? bf_lo(wA.y) * u0.z : 0.f) + ((3 < t) ? bf_hi(wA.y) * u0.w : 0.f) +
            ((4 < t) ? bf_lo(wA.z) * u1.x : 0.f) + ((5 < t) ? bf_hi(wA.z) * u1.y : 0.f) +
            ((6 < t) ? bf_lo(wA.w) * u1.z : 0.f);
      DB += ((0 < t) ? bf_lo(wB.x) * v0.x : 0.f) + ((1 < t) ? bf_hi(wB.x) * v0.y : 0.f) +
            ((2 < t) ? bf_lo(wB.y) * v0.z : 0.f) + ((3 < t) ? bf_hi(wB.y) * v0.w : 0.f) +
            ((4 < t) ? bf_lo(wB.z) * v1.x : 0.f) + ((5 < t) ? bf_hi(wB.z) * v1.y : 0.f) +
            ((6 < t) ? bf_lo(wB.w) * v1.z : 0.f);
    }
  }
  out[(size_t)(sb + s0) * 64 + lane] = DA;
  out[(size_t)(sb + s1) * 64 + lane] = DB;
}

// ---------------- launch ----------------
extern "C" void kernel_launch(void* const* d_in, const int* in_sizes, int n_in,
                              void* d_out, int out_size, void* d_ws, size_t ws_size,
                              hipStream_t stream) {
  const float* x   = (const float*)d_in[0];
  const float* Wd1 = (const float*)d_in[1];
  const float* bd1 = (const float*)d_in[2];
  const float* Wd2 = (const float*)d_in[3];
  const float* bd2 = (const float*)d_in[4];
  const float* Wdo = (const float*)d_in[5];
  const float* bdo = (const float*)d_in[6];
  const float* Wo1 = (const float*)d_in[7];
  const float* bo1 = (const float*)d_in[8];
  const float* Wo2 = (const float*)d_in[9];
  const float* bo2 = (const float*)d_in[10];
  const float* Woo = (const float*)d_in[11];
  const float* boo = (const float*)d_in[12];
  float* out = (float*)d_out;

  char* ws = (char*)d_ws;
  // Wcat (bf16 elems): Wo1@0 | Wo2@16384 | Wd1@81920 | Wd2@98304 | Wdo@163840
  __bf16* Wcat = (__bf16*)(ws + 0);          //   360448 B
  __bf16* Woob = (__bf16*)(ws + 360448);     //  1048576 B (zero-padded rows)
  __bf16* g2   = (__bf16*)(ws + 1409024);    // 16777216 B
  float*  xdp  = (float*)(ws + 18186240);    //  8388608 B
  const size_t zoff = 26574848;
  __bf16* zq   = (__bf16*)(ws + zoff);       // z slice buffer [QSs][2048] bf16

  const size_t zcap = (ws_size > zoff) ? (ws_size - zoff) : 0;
  int nslices = 4;
  if (zcap >= (size_t)B_TOT * ZROWB) nslices = 1;
  else if (zcap >= (size_t)(B_TOT / 2) * ZROWB) nslices = 2;
  const int QSs = B_TOT / nslices;
  const int nbm = QSs / 128;       // 128-sample tiles
  const int bmper = nbm >> 3;

  cast_all_kernel<<<512, 256, 0, stream>>>(
      Wo1, Wcat, HDIM * NDIM,
      Wo2, Wcat + 16384, HDIM * HDIM,
      Wd1, Wcat + 81920, HDIM * NDIM,
      Wd2, Wcat + 98304, HDIM * HDIM,
      Wdo, Wcat + 163840, NDIM * HDIM,
      Woo, Woob, OFFD * HDIM,
      Woob + OFFD * HDIM, 32 * HDIM);

  hipFuncSetAttribute((const void*)off_trunk_kernel,
                      hipFuncAttributeMaxDynamicSharedMemorySize, TRK_SMEM);
  hipFuncSetAttribute((const void*)diag_trunk_kernel,
                      hipFuncAttributeMaxDynamicSharedMemorySize, TRK_SMEM);
  off_trunk_kernel<<<B_TOT / 64, 512, TRK_SMEM, stream>>>(
      x, Wcat, bo1, bo2, g2);
  diag_trunk_kernel<<<B_TOT / 64, 512, TRK_SMEM, stream>>>(
      x, Wcat + 81920, bd1, bd2, bdo, xdp);

  hipFuncSetAttribute((const void*)gemm_z_kernel,
                      hipFuncAttributeMaxDynamicSharedMemorySize, GZ_SMEM);
  hipFuncSetAttribute((const void*)apply_kernel,
                      hipFuncAttributeMaxDynamicSharedMemorySize, APPLY_SMEM);
  for (int s = 0; s < nslices; ++s) {
    gemm_z_kernel<<<nbm * 16, 256, GZ_SMEM, stream>>>(
        g2 + (size_t)s * QSs * HDIM, Woob, boo, zq, bmper);
    apply_kernel<<<QSs / 16, 512, APPLY_SMEM, stream>>>(zq, xdp, x, out, s * QSs);
  }
}